// Round 2
// baseline (4583.910 us; speedup 1.0000x reference)
//
#include <hip/hip_runtime.h>
#include <hip/hip_bf16.h>

#define D 256
#define H 8
#define DK 32

typedef unsigned short ushort_t;
typedef unsigned int uint_t;

__device__ __forceinline__ float b2f(ushort_t u) {
    return __uint_as_float(((uint_t)u) << 16);
}
__device__ __forceinline__ ushort_t f2b(float f) {
    uint_t u = __float_as_uint(f);
    uint_t r = (u + 0x7FFFu + ((u >> 16) & 1u)) >> 16;   // RNE, NaN-unsafe (fine here)
    return (ushort_t)r;
}

// ---------------------------------------------------------------------------
// Zero-fill (grid-stride, float4)
// ---------------------------------------------------------------------------
__global__ void zero_fill(float* __restrict__ p, size_t n4) {
    size_t i = (size_t)blockIdx.x * blockDim.x + threadIdx.x;
    size_t stride = (size_t)gridDim.x * blockDim.x;
    float4 z = {0.f, 0.f, 0.f, 0.f};
    for (; i < n4; i += stride) ((float4*)p)[i] = z;
}

// ---------------------------------------------------------------------------
// Fold per-head w_att/w_msg (DK x DK) into Wk/Wv (D x D) and biases.
// grid: (D rows, 2 et, 2 which{0=k,1=v}), block 256
// ---------------------------------------------------------------------------
__global__ void fold_weights(const float* __restrict__ Wk, const float* __restrict__ bk,
                             const float* __restrict__ Wv, const float* __restrict__ bv,
                             const float* __restrict__ w_att, const float* __restrict__ w_msg,
                             float* __restrict__ Wkc, float* __restrict__ bkc,
                             float* __restrict__ Wvc, float* __restrict__ bvc) {
    int r = blockIdx.x, et = blockIdx.y, which = blockIdx.z;
    int tid = threadIdx.x;
    const float* Wsrc = (which ? Wv : Wk) + (size_t)et * D * D + (size_t)r * D;
    const float* wt   = (which ? w_msg : w_att) + (size_t)et * H * DK * DK;
    float* Wdst = (which ? Wvc : Wkc) + (size_t)et * D * D;
    __shared__ float wrow[D];
    wrow[tid] = Wsrc[tid];
    __syncthreads();
    int h = tid >> 5, j = tid & 31;
    const float* wth = wt + h * DK * DK;
    float acc = 0.f;
#pragma unroll 8
    for (int i = 0; i < DK; i++) acc += wrow[h * 32 + i] * wth[i * 32 + j];
    Wdst[(size_t)r * D + tid] = acc;
    if (r == 0) {
        const float* bsrc = (which ? bv : bk) + et * D;
        float* bdst = (which ? bvc : bkc) + et * D;
        float bacc = 0.f;
#pragma unroll 8
        for (int i = 0; i < DK; i++) bacc += bsrc[h * 32 + i] * wth[i * 32 + j];
        bdst[tid] = bacc;
    }
}

// ---------------------------------------------------------------------------
// C(MxD) = A(MxD) @ W(DxD) + bias, fp32 compute, bf16 output.
// BM=BN=64, BK=16, 256 thr, 4x4/thr
// ---------------------------------------------------------------------------
#define BM 64
#define BN 64
#define BK 16
__launch_bounds__(256)
__global__ void gemm_bias(const float* __restrict__ A, const float* __restrict__ W,
                          const float* __restrict__ bias, ushort_t* __restrict__ C, int M) {
    __shared__ float As[BK][BM + 1];
    __shared__ float Bs[BK][BN];
    int tid = threadIdx.x;
    int bm = blockIdx.x * BM;
    int bn = blockIdx.y * BN;
    int tx = tid & 15;
    int ty = tid >> 4;
    float acc[4][4] = {};
    int ka = tid & 15, ra = tid >> 4;
    int cb = tid & 63, kb0 = tid >> 6;
    for (int kc = 0; kc < D; kc += BK) {
#pragma unroll
        for (int j = 0; j < 4; j++) {
            int m = bm + ra + j * 16;
            As[ka][ra + j * 16] = (m < M) ? A[(size_t)m * D + kc + ka] : 0.0f;
        }
#pragma unroll
        for (int j = 0; j < 4; j++) {
            int kk = kb0 + j * 4;
            Bs[kk][cb] = W[(size_t)(kc + kk) * D + bn + cb];
        }
        __syncthreads();
#pragma unroll
        for (int k = 0; k < BK; k++) {
            float a0 = As[k][ty * 4 + 0], a1 = As[k][ty * 4 + 1];
            float a2 = As[k][ty * 4 + 2], a3 = As[k][ty * 4 + 3];
            float b0 = Bs[k][tx * 4 + 0], b1 = Bs[k][tx * 4 + 1];
            float b2 = Bs[k][tx * 4 + 2], b3 = Bs[k][tx * 4 + 3];
            acc[0][0] += a0 * b0; acc[0][1] += a0 * b1; acc[0][2] += a0 * b2; acc[0][3] += a0 * b3;
            acc[1][0] += a1 * b0; acc[1][1] += a1 * b1; acc[1][2] += a1 * b2; acc[1][3] += a1 * b3;
            acc[2][0] += a2 * b0; acc[2][1] += a2 * b1; acc[2][2] += a2 * b2; acc[2][3] += a2 * b3;
            acc[3][0] += a3 * b0; acc[3][1] += a3 * b1; acc[3][2] += a3 * b2; acc[3][3] += a3 * b3;
        }
        __syncthreads();
    }
#pragma unroll
    for (int i = 0; i < 4; i++) {
        int m = bm + ty * 4 + i;
        if (m < M) {
            int n = bn + tx * 4;
            ushort4 pk;
            pk.x = f2b(acc[i][0] + bias[n + 0]);
            pk.y = f2b(acc[i][1] + bias[n + 1]);
            pk.z = f2b(acc[i][2] + bias[n + 2]);
            pk.w = f2b(acc[i][3] + bias[n + 3]);
            *(ushort4*)(C + (size_t)m * D + n) = pk;
        }
    }
}

// ---------------------------------------------------------------------------
// Fused edge pass: wave per edge. Per head h (8 lanes each, 4 elems/lane):
//   p = q.k ; e = exp(p*mu*scale); Ssum[d,h] += e; Hbuf[d,:] += e * v[s,:]
// Normalization (by Ssum) deferred to node-level pass.
// grid: ((E+3)/4, 2 etypes), block 256
// ---------------------------------------------------------------------------
__global__ void edge_fused(const ushort_t* __restrict__ Qb, const ushort_t* __restrict__ Kb,
                           const ushort_t* __restrict__ Vb, const float* __restrict__ mu,
                           const int* __restrict__ src, const int* __restrict__ dst,
                           float* __restrict__ Ssum, float* __restrict__ Hbuf,
                           int N, int E) {
    int et = blockIdx.y;
    int wave = threadIdx.x >> 6, lane = threadIdx.x & 63;
    int e = blockIdx.x * 4 + wave;
    if (e >= E) return;
    int s = src[(size_t)et * E + e];
    int d = dst[(size_t)et * E + e];
    int dt = 1 - et;
    const ushort4* qrow = (const ushort4*)(Qb + ((size_t)dt * N + d) * D);
    const ushort4* krow = (const ushort4*)(Kb + ((size_t)et * N + s) * D);
    ushort4 qu = qrow[lane];
    ushort4 ku = krow[lane];
    float p = b2f(qu.x) * b2f(ku.x) + b2f(qu.y) * b2f(ku.y) +
              b2f(qu.z) * b2f(ku.z) + b2f(qu.w) * b2f(ku.w);
    p += __shfl_xor(p, 1);
    p += __shfl_xor(p, 2);
    p += __shfl_xor(p, 4);   // all 8 lanes of a head now hold the full dot
    int h = lane >> 3;
    float ex = expf(p * mu[et * H + h] * 0.17677669529663687f);
    if ((lane & 7) == 0)
        atomicAdd(&Ssum[((size_t)dt * N + d) * H + h], ex);
    const ushort4* vrow = (const ushort4*)(Vb + ((size_t)et * N + s) * D);
    ushort4 vu = vrow[lane];
    float* hrow = Hbuf + ((size_t)dt * N + d) * D + lane * 4;
    atomicAdd(&hrow[0], b2f(vu.x) * ex);
    atomicAdd(&hrow[1], b2f(vu.y) * ex);
    atomicAdd(&hrow[2], b2f(vu.z) * ex);
    atomicAdd(&hrow[3], b2f(vu.w) * ex);
}

// ---------------------------------------------------------------------------
// Hbuf[row, c] /= Ssum[row, c>>5]  (guard S==0: zero-in-degree nodes stay 0)
// one float4 per thread
// ---------------------------------------------------------------------------
__global__ void normalize(float* __restrict__ Hbuf, const float* __restrict__ Ssum,
                          size_t total4) {
    size_t i = (size_t)blockIdx.x * blockDim.x + threadIdx.x;
    if (i >= total4) return;
    size_t row = i >> 6;
    int c4 = (int)(i & 63);
    int h = c4 >> 3;
    float s = Ssum[row * H + h];
    float r = (s > 0.f) ? 1.0f / s : 0.0f;
    float4* p = (float4*)Hbuf + i;
    float4 v = *p;
    v.x *= r; v.y *= r; v.z *= r; v.w *= r;
    *p = v;
}

// ---------------------------------------------------------------------------
// out = LN(alpha*trans + (1-alpha)*feats) * ln_w + ln_b.  Block per row.
// ---------------------------------------------------------------------------
__global__ void skip_ln(const ushort_t* __restrict__ trans, const float* __restrict__ feats,
                        const float* __restrict__ lnw, const float* __restrict__ lnb,
                        const float* __restrict__ skip, float* __restrict__ out, int N) {
    int tid = threadIdx.x;
    size_t row = blockIdx.x;
    int t = (row >= (size_t)N) ? 1 : 0;
    float alpha = 1.0f / (1.0f + expf(-skip[t]));
    size_t base = row * D;
    float x = alpha * b2f(trans[base + tid]) + (1.0f - alpha) * feats[base + tid];
    float s = x, sq = x * x;
#pragma unroll
    for (int off = 1; off < 64; off <<= 1) {
        s  += __shfl_xor(s,  off);
        sq += __shfl_xor(sq, off);
    }
    __shared__ float ls[4], lq[4];
    int w = tid >> 6, l = tid & 63;
    if (l == 0) { ls[w] = s; lq[w] = sq; }
    __syncthreads();
    s  = ls[0] + ls[1] + ls[2] + ls[3];
    sq = lq[0] + lq[1] + lq[2] + lq[3];
    float mean = s * (1.0f / 256.0f);
    float var  = sq * (1.0f / 256.0f) - mean * mean;
    float r = rsqrtf(var + 1e-5f);
    out[base + tid] = (x - mean) * r * lnw[t * D + tid] + lnb[t * D + tid];
}

extern "C" void kernel_launch(void* const* d_in, const int* in_sizes, int n_in,
                              void* d_out, int out_size, void* d_ws, size_t ws_size,
                              hipStream_t stream) {
    const float* feats = (const float*)d_in[0];
    const float* Wk    = (const float*)d_in[1];
    const float* bk    = (const float*)d_in[2];
    const float* Wq    = (const float*)d_in[3];
    const float* bq    = (const float*)d_in[4];
    const float* Wv    = (const float*)d_in[5];
    const float* bv    = (const float*)d_in[6];
    const float* Wa    = (const float*)d_in[7];
    const float* ba    = (const float*)d_in[8];
    const float* ln_w  = (const float*)d_in[9];
    const float* ln_b  = (const float*)d_in[10];
    const float* skip  = (const float*)d_in[11];
    const float* mu    = (const float*)d_in[12];
    const float* w_att = (const float*)d_in[13];
    const float* w_msg = (const float*)d_in[14];
    const int*   src   = (const int*)d_in[15];
    const int*   dst   = (const int*)d_in[16];
    float* out = (float*)d_out;

    const int N = in_sizes[0] / (2 * D);
    const int E = in_sizes[15] / 2;
    const size_t ND2 = 2 * (size_t)N * D;     // elements in a (2,N,D) tensor

    // Workspace layout (float units). Total ~39M floats ~156 MB.
    float* ws = (float*)d_ws;
    size_t off = 0;
    float* Wkc  = ws + off; off += 2 * (size_t)D * D;
    float* Wvc  = ws + off; off += 2 * (size_t)D * D;
    float* bkc  = ws + off; off += 2 * D;
    float* bvc  = ws + off; off += 2 * D;
    ushort_t* Qb = (ushort_t*)(ws + off); off += ND2 / 2;   // bf16 (2,N,D)
    ushort_t* Kb = (ushort_t*)(ws + off); off += ND2 / 2;   // bf16; reused for trans
    ushort_t* Vb = (ushort_t*)(ws + off); off += ND2 / 2;
    float* Ssum = ws + off; off += 2 * (size_t)N * H;

    // Zero accumulators: Hbuf lives in d_out (fp32), Ssum in ws.
    zero_fill<<<1024, 256, 0, stream>>>(out, ND2 / 4);
    zero_fill<<<256, 256, 0, stream>>>(Ssum, (2 * (size_t)N * H) / 4);

    fold_weights<<<dim3(D, 2, 2), 256, 0, stream>>>(Wk, bk, Wv, bv, w_att, w_msg,
                                                    Wkc, bkc, Wvc, bvc);

    dim3 ggrid((N + BM - 1) / BM, D / BN);
    for (int t = 0; t < 2; t++)
        gemm_bias<<<ggrid, 256, 0, stream>>>(feats + (size_t)t * N * D, Wq + (size_t)t * D * D,
                                             bq + t * D, Qb + (size_t)t * N * D, N);
    for (int et = 0; et < 2; et++)
        gemm_bias<<<ggrid, 256, 0, stream>>>(feats + (size_t)et * N * D, Wkc + (size_t)et * D * D,
                                             bkc + et * D, Kb + (size_t)et * N * D, N);
    for (int et = 0; et < 2; et++)
        gemm_bias<<<ggrid, 256, 0, stream>>>(feats + (size_t)et * N * D, Wvc + (size_t)et * D * D,
                                             bvc + et * D, Vb + (size_t)et * N * D, N);

    dim3 egrid((E + 3) / 4, 2);
    edge_fused<<<egrid, 256, 0, stream>>>(Qb, Kb, Vb, mu, src, dst, Ssum, out, N, E);

    normalize<<<(unsigned)((ND2 / 4 + 255) / 256), 256, 0, stream>>>(out, Ssum, ND2 / 4);

    // trans = Hbuf @ Wa + ba  -> into Kb region (bf16), Hbuf read from d_out
    ushort_t* trans = Kb;
    for (int t = 0; t < 2; t++)
        gemm_bias<<<ggrid, 256, 0, stream>>>(out + (size_t)t * N * D, Wa + (size_t)t * D * D,
                                             ba + t * D, trans + (size_t)t * N * D, N);

    skip_ln<<<2 * N, 256, 0, stream>>>(trans, feats, ln_w, ln_b, skip, out, N);
}

// Round 3
// 1484.177 us; speedup vs baseline: 3.0885x; 3.0885x over previous
//
#include <hip/hip_runtime.h>
#include <hip/hip_bf16.h>

#define D 256
#define H 8
#define DK 32

typedef unsigned short ushort_t;
typedef unsigned int uint_t;

__device__ __forceinline__ float b2f(ushort_t u) {
    return __uint_as_float(((uint_t)u) << 16);
}
__device__ __forceinline__ ushort_t f2b(float f) {
    uint_t u = __float_as_uint(f);
    uint_t r = (u + 0x7FFFu + ((u >> 16) & 1u)) >> 16;   // RNE
    return (ushort_t)r;
}

// ---------------------------------------------------------------------------
// Zero int array
// ---------------------------------------------------------------------------
__global__ void zero_int(int* __restrict__ p, int n) {
    int i = blockIdx.x * blockDim.x + threadIdx.x;
    if (i < n) p[i] = 0;
}

// ---------------------------------------------------------------------------
// Fold per-head w_att/w_msg (DK x DK) into Wk/Wv (D x D) and biases.
// ---------------------------------------------------------------------------
__global__ void fold_weights(const float* __restrict__ Wk, const float* __restrict__ bk,
                             const float* __restrict__ Wv, const float* __restrict__ bv,
                             const float* __restrict__ w_att, const float* __restrict__ w_msg,
                             float* __restrict__ Wkc, float* __restrict__ bkc,
                             float* __restrict__ Wvc, float* __restrict__ bvc) {
    int r = blockIdx.x, et = blockIdx.y, which = blockIdx.z;
    int tid = threadIdx.x;
    const float* Wsrc = (which ? Wv : Wk) + (size_t)et * D * D + (size_t)r * D;
    const float* wt   = (which ? w_msg : w_att) + (size_t)et * H * DK * DK;
    float* Wdst = (which ? Wvc : Wkc) + (size_t)et * D * D;
    __shared__ float wrow[D];
    wrow[tid] = Wsrc[tid];
    __syncthreads();
    int h = tid >> 5, j = tid & 31;
    const float* wth = wt + h * DK * DK;
    float acc = 0.f;
#pragma unroll 8
    for (int i = 0; i < DK; i++) acc += wrow[h * 32 + i] * wth[i * 32 + j];
    Wdst[(size_t)r * D + tid] = acc;
    if (r == 0) {
        const float* bsrc = (which ? bv : bk) + et * D;
        float* bdst = (which ? bvc : bkc) + et * D;
        float bacc = 0.f;
#pragma unroll 8
        for (int i = 0; i < DK; i++) bacc += bsrc[h * 32 + i] * wth[i * 32 + j];
        bdst[tid] = bacc;
    }
}

// ---------------------------------------------------------------------------
// C(MxD) = A(MxD) @ W(DxD) + bias, fp32 compute, bf16 output.
// ---------------------------------------------------------------------------
#define BM 64
#define BN 64
#define BK 16
__launch_bounds__(256)
__global__ void gemm_bias(const float* __restrict__ A, const float* __restrict__ W,
                          const float* __restrict__ bias, ushort_t* __restrict__ C, int M) {
    __shared__ float As[BK][BM + 1];
    __shared__ float Bs[BK][BN];
    int tid = threadIdx.x;
    int bm = blockIdx.x * BM;
    int bn = blockIdx.y * BN;
    int tx = tid & 15;
    int ty = tid >> 4;
    float acc[4][4] = {};
    int ka = tid & 15, ra = tid >> 4;
    int cb = tid & 63, kb0 = tid >> 6;
    for (int kc = 0; kc < D; kc += BK) {
#pragma unroll
        for (int j = 0; j < 4; j++) {
            int m = bm + ra + j * 16;
            As[ka][ra + j * 16] = (m < M) ? A[(size_t)m * D + kc + ka] : 0.0f;
        }
#pragma unroll
        for (int j = 0; j < 4; j++) {
            int kk = kb0 + j * 4;
            Bs[kk][cb] = W[(size_t)(kc + kk) * D + bn + cb];
        }
        __syncthreads();
#pragma unroll
        for (int k = 0; k < BK; k++) {
            float a0 = As[k][ty * 4 + 0], a1 = As[k][ty * 4 + 1];
            float a2 = As[k][ty * 4 + 2], a3 = As[k][ty * 4 + 3];
            float b0 = Bs[k][tx * 4 + 0], b1 = Bs[k][tx * 4 + 1];
            float b2 = Bs[k][tx * 4 + 2], b3 = Bs[k][tx * 4 + 3];
            acc[0][0] += a0 * b0; acc[0][1] += a0 * b1; acc[0][2] += a0 * b2; acc[0][3] += a0 * b3;
            acc[1][0] += a1 * b0; acc[1][1] += a1 * b1; acc[1][2] += a1 * b2; acc[1][3] += a1 * b3;
            acc[2][0] += a2 * b0; acc[2][1] += a2 * b1; acc[2][2] += a2 * b2; acc[2][3] += a2 * b3;
            acc[3][0] += a3 * b0; acc[3][1] += a3 * b1; acc[3][2] += a3 * b2; acc[3][3] += a3 * b3;
        }
        __syncthreads();
    }
#pragma unroll
    for (int i = 0; i < 4; i++) {
        int m = bm + ty * 4 + i;
        if (m < M) {
            int n = bn + tx * 4;
            ushort4 pk;
            pk.x = f2b(acc[i][0] + bias[n + 0]);
            pk.y = f2b(acc[i][1] + bias[n + 1]);
            pk.z = f2b(acc[i][2] + bias[n + 2]);
            pk.w = f2b(acc[i][3] + bias[n + 3]);
            *(ushort4*)(C + (size_t)m * D + n) = pk;
        }
    }
}

// ---------------------------------------------------------------------------
// CSR build step 1: in-degree count. node id = dt*N + d, dt = 1-et.
// ---------------------------------------------------------------------------
__global__ void count_deg(const int* __restrict__ dst, int* __restrict__ deg,
                          int N, int E) {
    int i = blockIdx.x * blockDim.x + threadIdx.x;
    if (i >= 2 * E) return;
    int et = i / E, e = i - et * E;
    int d = dst[(size_t)et * E + e];
    atomicAdd(&deg[(1 - et) * N + d], 1);
}

// ---------------------------------------------------------------------------
// CSR build step 2: exclusive scan of deg (n=2N) -> row_ptr (n+1) and cursor.
// Single block, 1024 threads, sequential 1024-chunks.
// ---------------------------------------------------------------------------
__launch_bounds__(1024)
__global__ void scan_deg(const int* __restrict__ deg, int* __restrict__ row_ptr,
                         int* __restrict__ cursor, int n) {
    __shared__ int warp_scan[16];
    __shared__ int running;
    int tid = threadIdx.x;
    int lane = tid & 63, w = tid >> 6;
    if (tid == 0) running = 0;
    __syncthreads();
    for (int base = 0; base < n; base += 1024) {
        int i = base + tid;
        int v = (i < n) ? deg[i] : 0;
        int run = running;
        // inclusive scan within wave
        int x = v;
#pragma unroll
        for (int off = 1; off < 64; off <<= 1) {
            int y = __shfl_up(x, off);
            if (lane >= off) x += y;
        }
        if (lane == 63) warp_scan[w] = x;
        __syncthreads();
        if (tid < 16) {
            int t = warp_scan[tid];
#pragma unroll
            for (int off = 1; off < 16; off <<= 1) {
                int y = __shfl_up(t, off);
                if (tid >= off) t += y;
            }
            warp_scan[tid] = t;  // inclusive over waves
        }
        __syncthreads();
        int woff = w ? warp_scan[w - 1] : 0;
        if (i < n) {
            int excl = run + woff + x - v;
            row_ptr[i] = excl;
            cursor[i] = excl;
        }
        int total = warp_scan[15];
        __syncthreads();
        if (tid == 0) running = run + total;
        __syncthreads();
    }
    if (tid == 0) row_ptr[n] = running;
}

// ---------------------------------------------------------------------------
// CSR build step 3: scatter src ids into ebuf at cursor positions.
// ---------------------------------------------------------------------------
__global__ void fill_edges(const int* __restrict__ src, const int* __restrict__ dst,
                           int* __restrict__ cursor, int* __restrict__ ebuf,
                           int N, int E) {
    int i = blockIdx.x * blockDim.x + threadIdx.x;
    if (i >= 2 * E) return;
    int et = i / E, e = i - et * E;
    int d = dst[(size_t)et * E + e];
    int s = src[(size_t)et * E + e];
    int pos = atomicAdd(&cursor[(1 - et) * N + d], 1);
    ebuf[pos] = s;
}

// ---------------------------------------------------------------------------
// Node-centric aggregation: one wave per destination node (no atomics).
// Lane l holds elements 4l..4l+3 (head h = l>>3). For each incoming edge:
// dot(q,k) -> 8-lane reduce -> exp -> accumulate ssum and exp*v in registers.
// Write normalized fp32 row once.
// ---------------------------------------------------------------------------
__launch_bounds__(256)
__global__ void node_aggregate(const ushort_t* __restrict__ Qb, const ushort_t* __restrict__ Kb,
                               const ushort_t* __restrict__ Vb, const float* __restrict__ mu,
                               const int* __restrict__ row_ptr, const int* __restrict__ ebuf,
                               float* __restrict__ out, int N) {
    int wid = (blockIdx.x * blockDim.x + threadIdx.x) >> 6;
    int lane = threadIdx.x & 63;
    if (wid >= 2 * N) return;
    int dt = (wid >= N) ? 1 : 0;
    int et = 1 - dt;
    int h = lane >> 3;
    const ushort4* qrow = (const ushort4*)(Qb + (size_t)wid * D);
    ushort4 qu = qrow[lane];
    float q0 = b2f(qu.x), q1 = b2f(qu.y), q2 = b2f(qu.z), q3 = b2f(qu.w);
    float sc = mu[et * H + h] * 0.17677669529663687f;  // 1/sqrt(32)
    int beg = row_ptr[wid], end = row_ptr[wid + 1];
    const ushort_t* Kbase = Kb + (size_t)et * N * D;
    const ushort_t* Vbase = Vb + (size_t)et * N * D;
    float a0 = 0.f, a1 = 0.f, a2 = 0.f, a3 = 0.f, ssum = 0.f;
    for (int idx = beg; idx < end; idx++) {
        int s = ebuf[idx];
        ushort4 ku = ((const ushort4*)(Kbase + (size_t)s * D))[lane];
        ushort4 vu = ((const ushort4*)(Vbase + (size_t)s * D))[lane];
        float p = q0 * b2f(ku.x) + q1 * b2f(ku.y) + q2 * b2f(ku.z) + q3 * b2f(ku.w);
        p += __shfl_xor(p, 1);
        p += __shfl_xor(p, 2);
        p += __shfl_xor(p, 4);
        float ex = expf(p * sc);
        ssum += ex;
        a0 += ex * b2f(vu.x);
        a1 += ex * b2f(vu.y);
        a2 += ex * b2f(vu.z);
        a3 += ex * b2f(vu.w);
    }
    float r = (ssum > 0.f) ? 1.0f / ssum : 0.0f;
    float4 res = {a0 * r, a1 * r, a2 * r, a3 * r};
    ((float4*)(out + (size_t)wid * D))[lane] = res;
}

// ---------------------------------------------------------------------------
// out = LN(alpha*trans + (1-alpha)*feats) * ln_w + ln_b.  Block per row.
// ---------------------------------------------------------------------------
__global__ void skip_ln(const ushort_t* __restrict__ trans, const float* __restrict__ feats,
                        const float* __restrict__ lnw, const float* __restrict__ lnb,
                        const float* __restrict__ skip, float* __restrict__ out, int N) {
    int tid = threadIdx.x;
    size_t row = blockIdx.x;
    int t = (row >= (size_t)N) ? 1 : 0;
    float alpha = 1.0f / (1.0f + expf(-skip[t]));
    size_t base = row * D;
    float x = alpha * b2f(trans[base + tid]) + (1.0f - alpha) * feats[base + tid];
    float s = x, sq = x * x;
#pragma unroll
    for (int off = 1; off < 64; off <<= 1) {
        s  += __shfl_xor(s,  off);
        sq += __shfl_xor(sq, off);
    }
    __shared__ float ls[4], lq[4];
    int w = tid >> 6, l = tid & 63;
    if (l == 0) { ls[w] = s; lq[w] = sq; }
    __syncthreads();
    s  = ls[0] + ls[1] + ls[2] + ls[3];
    sq = lq[0] + lq[1] + lq[2] + lq[3];
    float mean = s * (1.0f / 256.0f);
    float var  = sq * (1.0f / 256.0f) - mean * mean;
    float r = rsqrtf(var + 1e-5f);
    out[base + tid] = (x - mean) * r * lnw[t * D + tid] + lnb[t * D + tid];
}

extern "C" void kernel_launch(void* const* d_in, const int* in_sizes, int n_in,
                              void* d_out, int out_size, void* d_ws, size_t ws_size,
                              hipStream_t stream) {
    const float* feats = (const float*)d_in[0];
    const float* Wk    = (const float*)d_in[1];
    const float* bk    = (const float*)d_in[2];
    const float* Wq    = (const float*)d_in[3];
    const float* bq    = (const float*)d_in[4];
    const float* Wv    = (const float*)d_in[5];
    const float* bv    = (const float*)d_in[6];
    const float* Wa    = (const float*)d_in[7];
    const float* ba    = (const float*)d_in[8];
    const float* ln_w  = (const float*)d_in[9];
    const float* ln_b  = (const float*)d_in[10];
    const float* skip  = (const float*)d_in[11];
    const float* mu    = (const float*)d_in[12];
    const float* w_att = (const float*)d_in[13];
    const float* w_msg = (const float*)d_in[14];
    const int*   src   = (const int*)d_in[15];
    const int*   dst   = (const int*)d_in[16];
    float* out = (float*)d_out;

    const int N = in_sizes[0] / (2 * D);
    const int E = in_sizes[15] / 2;
    const size_t ND2 = 2 * (size_t)N * D;
    const int NN = 2 * N;

    // Workspace layout (float units). ~84 MB total.
    float* ws = (float*)d_ws;
    size_t off = 0;
    float* Wkc  = ws + off; off += 2 * (size_t)D * D;
    float* Wvc  = ws + off; off += 2 * (size_t)D * D;
    float* bkc  = ws + off; off += 2 * D;
    float* bvc  = ws + off; off += 2 * D;
    ushort_t* Qb = (ushort_t*)(ws + off); off += ND2 / 2;   // bf16 (2,N,D)
    ushort_t* Kb = (ushort_t*)(ws + off); off += ND2 / 2;   // bf16; reused for trans
    ushort_t* Vb = (ushort_t*)(ws + off); off += ND2 / 2;
    int* deg     = (int*)(ws + off); off += NN;
    int* row_ptr = (int*)(ws + off); off += NN + 1;
    int* cursor  = (int*)(ws + off); off += NN;
    int* ebuf    = (int*)(ws + off); off += 2 * (size_t)E;

    // --- CSR build (overlaps nothing; cheap) ---
    zero_int<<<(NN + 255) / 256, 256, 0, stream>>>(deg, NN);
    count_deg<<<(2 * E + 255) / 256, 256, 0, stream>>>(dst, deg, N, E);
    scan_deg<<<1, 1024, 0, stream>>>(deg, row_ptr, cursor, NN);
    fill_edges<<<(2 * E + 255) / 256, 256, 0, stream>>>(src, dst, cursor, ebuf, N, E);

    fold_weights<<<dim3(D, 2, 2), 256, 0, stream>>>(Wk, bk, Wv, bv, w_att, w_msg,
                                                    Wkc, bkc, Wvc, bvc);

    dim3 ggrid((N + BM - 1) / BM, D / BN);
    for (int t = 0; t < 2; t++)
        gemm_bias<<<ggrid, 256, 0, stream>>>(feats + (size_t)t * N * D, Wq + (size_t)t * D * D,
                                             bq + t * D, Qb + (size_t)t * N * D, N);
    for (int et = 0; et < 2; et++)
        gemm_bias<<<ggrid, 256, 0, stream>>>(feats + (size_t)et * N * D, Wkc + (size_t)et * D * D,
                                             bkc + et * D, Kb + (size_t)et * N * D, N);
    for (int et = 0; et < 2; et++)
        gemm_bias<<<ggrid, 256, 0, stream>>>(feats + (size_t)et * N * D, Wvc + (size_t)et * D * D,
                                             bvc + et * D, Vb + (size_t)et * N * D, N);

    // --- node-centric attention aggregation (no atomics), writes fp32 into out ---
    node_aggregate<<<(NN * 64 + 255) / 256, 256, 0, stream>>>(Qb, Kb, Vb, mu,
                                                              row_ptr, ebuf, out, N);

    // trans = Hbuf @ Wa + ba -> Kb region (bf16)
    ushort_t* trans = Kb;
    for (int t = 0; t < 2; t++)
        gemm_bias<<<ggrid, 256, 0, stream>>>(out + (size_t)t * N * D, Wa + (size_t)t * D * D,
                                             ba + t * D, trans + (size_t)t * N * D, N);

    skip_ln<<<2 * N, 256, 0, stream>>>(trans, feats, ln_w, ln_b, skip, out, N);
}

// Round 4
// 802.277 us; speedup vs baseline: 5.7136x; 1.8500x over previous
//
#include <hip/hip_runtime.h>
#include <hip/hip_bf16.h>

#define D 256
#define H 8
#define DK 32

typedef unsigned short ushort_t;
typedef unsigned int uint_t;
typedef __attribute__((ext_vector_type(4))) float floatx4;
typedef __attribute__((ext_vector_type(8))) short shortx8;

typedef __attribute__((address_space(3))) void lds_void_t;
typedef const __attribute__((address_space(1))) void gbl_void_t;

__device__ __forceinline__ float b2f(ushort_t u) {
    return __uint_as_float(((uint_t)u) << 16);
}
__device__ __forceinline__ ushort_t f2b(float f) {
    uint_t u = __float_as_uint(f);
    uint_t r = (u + 0x7FFFu + ((u >> 16) & 1u)) >> 16;   // RNE
    return (ushort_t)r;
}
__device__ __forceinline__ void async_cp16(const void* g, void* l) {
    __builtin_amdgcn_global_load_lds((gbl_void_t*)g, (lds_void_t*)l, 16, 0, 0);
}

// ---------------------------------------------------------------------------
// feats fp32 -> bf16 (vectorized)
// ---------------------------------------------------------------------------
__global__ void cvt_bf16(const float* __restrict__ in, ushort_t* __restrict__ out, size_t n4) {
    size_t i = (size_t)blockIdx.x * blockDim.x + threadIdx.x;
    if (i >= n4) return;
    float4 v = ((const float4*)in)[i];
    ushort4 o;
    o.x = f2b(v.x); o.y = f2b(v.y); o.z = f2b(v.z); o.w = f2b(v.w);
    ((ushort4*)out)[i] = o;
}

__global__ void zero_int(int* __restrict__ p, int n) {
    int i = blockIdx.x * blockDim.x + threadIdx.x;
    if (i < n) p[i] = 0;
}

// ---------------------------------------------------------------------------
// Fold per-head w_att/w_msg into Wk/Wv (fp32, D x D) and biases.
// ---------------------------------------------------------------------------
__global__ void fold_weights(const float* __restrict__ Wk, const float* __restrict__ bk,
                             const float* __restrict__ Wv, const float* __restrict__ bv,
                             const float* __restrict__ w_att, const float* __restrict__ w_msg,
                             float* __restrict__ Wkc, float* __restrict__ bkc,
                             float* __restrict__ Wvc, float* __restrict__ bvc) {
    int r = blockIdx.x, et = blockIdx.y, which = blockIdx.z;
    int tid = threadIdx.x;
    const float* Wsrc = (which ? Wv : Wk) + (size_t)et * D * D + (size_t)r * D;
    const float* wt   = (which ? w_msg : w_att) + (size_t)et * H * DK * DK;
    float* Wdst = (which ? Wvc : Wkc) + (size_t)et * D * D;
    __shared__ float wrow[D];
    wrow[tid] = Wsrc[tid];
    __syncthreads();
    int h = tid >> 5, j = tid & 31;
    const float* wth = wt + h * DK * DK;
    float acc = 0.f;
#pragma unroll 8
    for (int i = 0; i < DK; i++) acc += wrow[h * 32 + i] * wth[i * 32 + j];
    Wdst[(size_t)r * D + tid] = acc;
    if (r == 0) {
        const float* bsrc = (which ? bv : bk) + et * D;
        float* bdst = (which ? bvc : bkc) + et * D;
        float bacc = 0.f;
#pragma unroll 8
        for (int i = 0; i < DK; i++) bacc += bsrc[h * 32 + i] * wth[i * 32 + j];
        bdst[tid] = bacc;
    }
}

// ---------------------------------------------------------------------------
// Pack transposed bf16 weights:
//   WT_all[t][n][k], n in [0,768): {Wq | Wkc | Wvc}[t][k][n%256]
//   WaT[t][n][k] = Wa[t][k][n]
//   bias_all[t][n] = {bq | bkc | bvc}
// ---------------------------------------------------------------------------
__global__ void pack_weights(const float* __restrict__ Wq, const float* __restrict__ bq,
                             const float* __restrict__ Wkc, const float* __restrict__ bkc,
                             const float* __restrict__ Wvc, const float* __restrict__ bvc,
                             const float* __restrict__ Wa,
                             ushort_t* __restrict__ WT_all, ushort_t* __restrict__ WaT,
                             float* __restrict__ bias_all) {
    int idx = blockIdx.x * blockDim.x + threadIdx.x;
    const int NW = 2 * 768 * 256;
    if (idx < NW) {
        int t = idx / (768 * 256);
        int rem = idx - t * 768 * 256;
        int n = rem >> 8, k = rem & 255;
        int sec = n >> 8, nn = n & 255;
        const float* W = (sec == 0) ? Wq : (sec == 1) ? Wkc : Wvc;
        WT_all[idx] = f2b(W[(size_t)t * D * D + (size_t)k * D + nn]);
    } else if (idx < NW + 2 * 256 * 256) {
        int r = idx - NW;
        int t = r / (256 * 256);
        int rem = r - t * 256 * 256;
        int n = rem >> 8, k = rem & 255;
        WaT[r] = f2b(Wa[(size_t)t * D * D + (size_t)k * D + n]);
    }
    if (idx < 2 * 768) {
        int t = idx / 768, n = idx % 768;
        int sec = n >> 8, nn = n & 255;
        const float* b = (sec == 0) ? bq : (sec == 1) ? bkc : bvc;
        bias_all[idx] = b[t * D + nn];
    }
}

// ---------------------------------------------------------------------------
// bf16 MFMA GEMM: C(M x Ncols) = A(M x 256, stride lda) @ BT^T + bias
// BT is (Ncols x 256) row-major (i.e. B transposed). Output bf16, stride ldc.
// 128x128 tile, 256 thr / 4 waves, 4x4 16x16x32 MFMA per wave,
// global_load_lds width-16 staging (LDS tiles MUST be unpadded & contiguous).
// ---------------------------------------------------------------------------
#define TM 128
#define TN 128
#define TKK 32
__launch_bounds__(256)
__global__ void gemm_mfma(const ushort_t* __restrict__ A, int lda,
                          const ushort_t* __restrict__ BT,
                          const float* __restrict__ bias,
                          ushort_t* __restrict__ C, int ldc, int M) {
    __shared__ ushort_t As[TM * TKK];   // 8 KB
    __shared__ ushort_t Bs[TN * TKK];   // 8 KB
    int tid = threadIdx.x;
    int w = tid >> 6, lane = tid & 63;
    int bm = blockIdx.x * TM;
    int bn = blockIdx.y * TN;
    int wm = (w & 1) * 64, wn = (w >> 1) * 64;

    floatx4 acc[4][4] = {};

    int srow = lane >> 2;            // 0..15 rows per instruction
    int scol = (lane & 3) * 8;       // k offset (ushorts)

    for (int kc = 0; kc < 256; kc += TKK) {
#pragma unroll
        for (int j = 0; j < 2; j++) {
            int r = w * 32 + j * 16;                  // tile row block (wave-uniform)
            int gr = bm + r + srow; if (gr >= M) gr = M - 1;
            async_cp16(A + (size_t)gr * lda + kc + scol, As + r * TKK);
            int gn = bn + r + srow;                   // BT row = output col
            async_cp16(BT + (size_t)gn * 256 + kc + scol, Bs + r * TKK);
        }
        __builtin_amdgcn_s_waitcnt(0x0F70);           // vmcnt(0)
        __syncthreads();

        int fr = lane & 15, fq = lane >> 4;
        shortx8 af[4], bf[4];
#pragma unroll
        for (int i = 0; i < 4; i++)
            af[i] = *(const shortx8*)(As + (wm + i * 16 + fr) * TKK + fq * 8);
#pragma unroll
        for (int j = 0; j < 4; j++)
            bf[j] = *(const shortx8*)(Bs + (wn + j * 16 + fr) * TKK + fq * 8);
#pragma unroll
        for (int i = 0; i < 4; i++)
#pragma unroll
            for (int j = 0; j < 4; j++)
                acc[i][j] = __builtin_amdgcn_mfma_f32_16x16x32_bf16(af[i], bf[j], acc[i][j], 0, 0, 0);
        __syncthreads();
    }

    int fr = lane & 15, fq = lane >> 4;
#pragma unroll
    for (int i = 0; i < 4; i++) {
#pragma unroll
        for (int j = 0; j < 4; j++) {
            int col = bn + wn + j * 16 + fr;
            float bv = bias[col];
#pragma unroll
            for (int r = 0; r < 4; r++) {
                int row = bm + wm + i * 16 + fq * 4 + r;
                if (row < M) C[(size_t)row * ldc + col] = f2b(acc[i][j][r] + bv);
            }
        }
    }
}

// ---------------------------------------------------------------------------
// CSR build
// ---------------------------------------------------------------------------
__global__ void count_deg(const int* __restrict__ dst, int* __restrict__ deg,
                          int N, int E) {
    int i = blockIdx.x * blockDim.x + threadIdx.x;
    if (i >= 2 * E) return;
    int et = i / E, e = i - et * E;
    int d = dst[(size_t)et * E + e];
    atomicAdd(&deg[(1 - et) * N + d], 1);
}

__launch_bounds__(1024)
__global__ void scan_deg(const int* __restrict__ deg, int* __restrict__ row_ptr,
                         int* __restrict__ cursor, int n) {
    __shared__ int warp_scan[16];
    __shared__ int running;
    int tid = threadIdx.x;
    int lane = tid & 63, w = tid >> 6;
    if (tid == 0) running = 0;
    __syncthreads();
    for (int base = 0; base < n; base += 1024) {
        int i = base + tid;
        int v = (i < n) ? deg[i] : 0;
        int run = running;
        int x = v;
#pragma unroll
        for (int off = 1; off < 64; off <<= 1) {
            int y = __shfl_up(x, off);
            if (lane >= off) x += y;
        }
        if (lane == 63) warp_scan[w] = x;
        __syncthreads();
        if (tid < 16) {
            int t = warp_scan[tid];
#pragma unroll
            for (int off = 1; off < 16; off <<= 1) {
                int y = __shfl_up(t, off);
                if (tid >= off) t += y;
            }
            warp_scan[tid] = t;
        }
        __syncthreads();
        int woff = w ? warp_scan[w - 1] : 0;
        if (i < n) {
            int excl = run + woff + x - v;
            row_ptr[i] = excl;
            cursor[i] = excl;
        }
        int total = warp_scan[15];
        __syncthreads();
        if (tid == 0) running = run + total;
        __syncthreads();
    }
    if (tid == 0) row_ptr[n] = running;
}

__global__ void fill_edges(const int* __restrict__ src, const int* __restrict__ dst,
                           int* __restrict__ cursor, int* __restrict__ ebuf,
                           int N, int E) {
    int i = blockIdx.x * blockDim.x + threadIdx.x;
    if (i >= 2 * E) return;
    int et = i / E, e = i - et * E;
    int d = dst[(size_t)et * E + e];
    int s = src[(size_t)et * E + e];
    int pos = atomicAdd(&cursor[(1 - et) * N + d], 1);
    ebuf[pos] = s;
}

// ---------------------------------------------------------------------------
// Node-centric aggregation over interleaved QKV buffer [t][node][Q|K|V] (768).
// One wave per destination node. Writes normalized H (bf16) OVER its own Q
// section (safe: each Q row is read exactly once, by its owning wave, before
// the write; K/V sections are disjoint columns).
// ---------------------------------------------------------------------------
__launch_bounds__(256)
__global__ void node_aggregate(ushort_t* __restrict__ QKV, const float* __restrict__ mu,
                               const int* __restrict__ row_ptr, const int* __restrict__ ebuf,
                               int N) {
    int wid = (blockIdx.x * blockDim.x + threadIdx.x) >> 6;
    int lane = threadIdx.x & 63;
    if (wid >= 2 * N) return;
    int dt = (wid >= N) ? 1 : 0;
    int et = 1 - dt;
    int h = lane >> 3;
    ushort4 qu = ((const ushort4*)(QKV + (size_t)wid * 768))[lane];
    float q0 = b2f(qu.x), q1 = b2f(qu.y), q2 = b2f(qu.z), q3 = b2f(qu.w);
    float sc = mu[et * H + h] * 0.17677669529663687f;  // 1/sqrt(32)
    int beg = row_ptr[wid], end = row_ptr[wid + 1];
    const ushort_t* KVb = QKV + (size_t)et * N * 768;
    float a0 = 0.f, a1 = 0.f, a2 = 0.f, a3 = 0.f, ssum = 0.f;
    for (int idx = beg; idx < end; idx++) {
        int s = ebuf[idx];
        const ushort_t* srow = KVb + (size_t)s * 768;
        ushort4 ku = ((const ushort4*)(srow + 256))[lane];
        ushort4 vu = ((const ushort4*)(srow + 512))[lane];
        float p = q0 * b2f(ku.x) + q1 * b2f(ku.y) + q2 * b2f(ku.z) + q3 * b2f(ku.w);
        p += __shfl_xor(p, 1);
        p += __shfl_xor(p, 2);
        p += __shfl_xor(p, 4);
        float ex = expf(p * sc);
        ssum += ex;
        a0 += ex * b2f(vu.x);
        a1 += ex * b2f(vu.y);
        a2 += ex * b2f(vu.z);
        a3 += ex * b2f(vu.w);
    }
    float r = (ssum > 0.f) ? 1.0f / ssum : 0.0f;
    ushort4 h4;
    h4.x = f2b(a0 * r); h4.y = f2b(a1 * r); h4.z = f2b(a2 * r); h4.w = f2b(a3 * r);
    ((ushort4*)(QKV + (size_t)wid * 768))[lane] = h4;
}

// ---------------------------------------------------------------------------
// out = LN(alpha*trans + (1-alpha)*feats) * ln_w + ln_b.  Block per row.
// ---------------------------------------------------------------------------
__global__ void skip_ln(const ushort_t* __restrict__ trans, const float* __restrict__ feats,
                        const float* __restrict__ lnw, const float* __restrict__ lnb,
                        const float* __restrict__ skip, float* __restrict__ out, int N) {
    int tid = threadIdx.x;
    size_t row = blockIdx.x;
    int t = (row >= (size_t)N) ? 1 : 0;
    float alpha = 1.0f / (1.0f + expf(-skip[t]));
    size_t base = row * D;
    float x = alpha * b2f(trans[base + tid]) + (1.0f - alpha) * feats[base + tid];
    float s = x, sq = x * x;
#pragma unroll
    for (int off = 1; off < 64; off <<= 1) {
        s  += __shfl_xor(s,  off);
        sq += __shfl_xor(sq, off);
    }
    __shared__ float ls[4], lq[4];
    int w = tid >> 6, l = tid & 63;
    if (l == 0) { ls[w] = s; lq[w] = sq; }
    __syncthreads();
    s  = ls[0] + ls[1] + ls[2] + ls[3];
    sq = lq[0] + lq[1] + lq[2] + lq[3];
    float mean = s * (1.0f / 256.0f);
    float var  = sq * (1.0f / 256.0f) - mean * mean;
    float r = rsqrtf(var + 1e-5f);
    out[base + tid] = (x - mean) * r * lnw[t * D + tid] + lnb[t * D + tid];
}

extern "C" void kernel_launch(void* const* d_in, const int* in_sizes, int n_in,
                              void* d_out, int out_size, void* d_ws, size_t ws_size,
                              hipStream_t stream) {
    const float* feats = (const float*)d_in[0];
    const float* Wk    = (const float*)d_in[1];
    const float* bk    = (const float*)d_in[2];
    const float* Wq    = (const float*)d_in[3];
    const float* bq    = (const float*)d_in[4];
    const float* Wv    = (const float*)d_in[5];
    const float* bv    = (const float*)d_in[6];
    const float* Wa    = (const float*)d_in[7];
    const float* ba    = (const float*)d_in[8];
    const float* ln_w  = (const float*)d_in[9];
    const float* ln_b  = (const float*)d_in[10];
    const float* skip  = (const float*)d_in[11];
    const float* mu    = (const float*)d_in[12];
    const float* w_att = (const float*)d_in[13];
    const float* w_msg = (const float*)d_in[14];
    const int*   src   = (const int*)d_in[15];
    const int*   dst   = (const int*)d_in[16];
    float* out = (float*)d_out;

    const int N = in_sizes[0] / (2 * D);
    const int E = in_sizes[15] / 2;
    const int NN = 2 * N;
    const size_t ND2 = 2 * (size_t)N * D;     // 25.6M elems

    // Workspace layout (float units). ~212 MB total.
    float* ws = (float*)d_ws;
    size_t off = 0;
    float* Wkc  = ws + off; off += 2 * (size_t)D * D;
    float* Wvc  = ws + off; off += 2 * (size_t)D * D;
    float* bkc  = ws + off; off += 2 * D;
    float* bvc  = ws + off; off += 2 * D;
    float* bias_all = ws + off; off += 2 * 768;
    ushort_t* WT_all = (ushort_t*)(ws + off); off += 2 * 768 * 256 / 2;
    ushort_t* WaT    = (ushort_t*)(ws + off); off += 2 * 256 * 256 / 2;
    ushort_t* featsb = (ushort_t*)(ws + off); off += ND2 / 2;   // bf16; reused for trans
    ushort_t* QKV    = (ushort_t*)(ws + off); off += 2 * (size_t)N * 768 / 2;
    int* deg     = (int*)(ws + off); off += NN;
    int* row_ptr = (int*)(ws + off); off += NN + 1;
    int* cursor  = (int*)(ws + off); off += NN + 1;
    int* ebuf    = (int*)(ws + off); off += 2 * (size_t)E;

    // --- CSR build ---
    zero_int<<<(NN + 255) / 256, 256, 0, stream>>>(deg, NN);
    count_deg<<<(2 * E + 255) / 256, 256, 0, stream>>>(dst, deg, N, E);
    scan_deg<<<1, 1024, 0, stream>>>(deg, row_ptr, cursor, NN);
    fill_edges<<<(2 * E + 255) / 256, 256, 0, stream>>>(src, dst, cursor, ebuf, N, E);

    // --- weight prep ---
    fold_weights<<<dim3(D, 2, 2), 256, 0, stream>>>(Wk, bk, Wv, bv, w_att, w_msg,
                                                    Wkc, bkc, Wvc, bvc);
    pack_weights<<<(2 * 768 * 256 + 2 * 256 * 256 + 255) / 256, 256, 0, stream>>>(
        Wq, bq, Wkc, bkc, Wvc, bvc, Wa, WT_all, WaT, bias_all);

    // --- feats -> bf16 ---
    cvt_bf16<<<(unsigned)((ND2 / 4 + 255) / 256), 256, 0, stream>>>(feats, featsb, ND2 / 4);

    // --- fused Q|K|V GEMM per ntype: (N x 256) @ (256 x 768) ---
    dim3 qkv_grid((N + TM - 1) / TM, 768 / TN);
    for (int t = 0; t < 2; t++)
        gemm_mfma<<<qkv_grid, 256, 0, stream>>>(featsb + (size_t)t * N * D, D,
                                                WT_all + (size_t)t * 768 * 256,
                                                bias_all + t * 768,
                                                QKV + (size_t)t * N * 768, 768, N);

    // --- attention aggregation (H overwrites Q section, bf16) ---
    node_aggregate<<<(NN * 64 + 255) / 256, 256, 0, stream>>>(QKV, mu, row_ptr, ebuf, N);

    // --- trans = H @ Wa + ba -> featsb region (bf16) ---
    ushort_t* transb = featsb;
    dim3 tr_grid((N + TM - 1) / TM, 256 / TN);
    for (int t = 0; t < 2; t++)
        gemm_mfma<<<tr_grid, 256, 0, stream>>>(QKV + (size_t)t * N * 768, 768,
                                               WaT + (size_t)t * 256 * 256,
                                               ba + t * 256,
                                               transb + (size_t)t * N * D, D, N);

    skip_ln<<<2 * N, 256, 0, stream>>>(transb, feats, ln_w, ln_b, skip, out, N);
}